// Round 5
// baseline (1990.622 us; speedup 1.0000x reference)
//
#include <hip/hip_runtime.h>
#include <hip/hip_bf16.h>

// CharDecoder: T=21, B=4096, H=1024, E=50, V=96
// d_out: scores(T,B,V) fp32 | h_T(B,H) | c_T(B,H)

#define T_STEPS 21
#define BSZ 4096
#define HDIM 1024
#define VOCAB 96
#define EDIM 50

typedef __attribute__((ext_vector_type(8))) short short8;
typedef __attribute__((ext_vector_type(4))) short shortx4;
typedef __attribute__((ext_vector_type(4))) float f32x4;

#define GLL16(g, l)                                                        \
  __builtin_amdgcn_global_load_lds(                                        \
      (const __attribute__((address_space(1))) void*)(g),                  \
      (__attribute__((address_space(3))) void*)(l), 16, 0, 0)

#define ASM_BARRIER() asm volatile("s_barrier" ::: "memory")
#define ASM_VMCNT4() asm volatile("s_waitcnt vmcnt(4)" ::: "memory")
#define ASM_VMCNT0() asm volatile("s_waitcnt vmcnt(0)" ::: "memory")

__device__ __forceinline__ float sigmoidf_fast(float x) {
  return 1.0f / (1.0f + __expf(-x));
}
__device__ __forceinline__ float tanhf_fast(float x) {
  return 2.0f / (1.0f + __expf(-2.0f * x)) - 1.0f;
}
__device__ __forceinline__ float b2f(short s) {
  return __uint_as_float(((unsigned int)(unsigned short)s) << 16);
}

// ---- prep: fp32 -> bf16 weight/state conversion + barrier reset ---------
__global__ void prep_convert(const float* __restrict__ Whh_f,
                             const float* __restrict__ Wout_f,
                             const float* __restrict__ h0,
                             __hip_bfloat16* __restrict__ Whh,
                             __hip_bfloat16* __restrict__ Wout,
                             __hip_bfloat16* __restrict__ hb0,
                             int* __restrict__ bars) {
  int idx = blockIdx.x * 256 + threadIdx.x;
  if (blockIdx.x == 0 && threadIdx.x < 16) bars[threadIdx.x] = 0;
  if (idx < 4 * HDIM * HDIM) {
    Whh[idx] = __float2bfloat16(Whh_f[idx]);
    hb0[idx] = __float2bfloat16(h0[idx]);
  }
  if (idx < VOCAB * HDIM) Wout[idx] = __float2bfloat16(Wout_f[idx]);
}

// ---- prep: Pb[j>>6][v][unit 64][gate 4] (bf16) = emb.W_ih + b_ih + b_hh -
__global__ void prep_ptable(const float* __restrict__ emb,
                            const float* __restrict__ Wih,
                            const float* __restrict__ bih,
                            const float* __restrict__ bhh,
                            __hip_bfloat16* __restrict__ Pb) {
  int idx = blockIdx.x * 256 + threadIdx.x;  // 96*4096
  int v = idx >> 12, g = idx & 4095;         // g = gate*1024 + j
  int gate = g >> 10, j = g & 1023;
  const float* er = emb + v * EDIM;
  const float* wr = Wih + g * EDIM;
  float s = bih[g] + bhh[g];
#pragma unroll 10
  for (int e = 0; e < EDIM; ++e) s += er[e] * wr[e];
  Pb[(size_t)(j >> 6) * 24576 + v * 256 + (j & 63) * 4 + gate] =
      __float2bfloat16(s);
}

// ---- shared 256x256 8-phase GEMM machinery (R4, verified) ---------------
#define STAGE_A(h, kt, b)                                                   \
  do {                                                                      \
    GLL16(hprev + aSrc[0] + (size_t)(h) * 131072 + (size_t)(kt) * 64,       \
          smem + ((b) << 16) + ((h) << 14) + aDst[0]);                      \
    GLL16(hprev + aSrc[1] + (size_t)(h) * 131072 + (size_t)(kt) * 64,       \
          smem + ((b) << 16) + ((h) << 14) + aDst[1]);                      \
  } while (0)

#define STAGE_B(h, kt, b)                                                   \
  do {                                                                      \
    GLL16(Whh + bSrc[h][0] + (size_t)(kt) * 64,                             \
          smem + ((b) << 16) + bDst[h][0]);                                 \
    GLL16(Whh + bSrc[h][1] + (size_t)(kt) * 64,                             \
          smem + ((b) << 16) + bDst[h][1]);                                 \
  } while (0)

#define PHASE(mh, nh, STAGE_STMT, VM_STMT)                                  \
  {                                                                         \
    short8 af[8], bf[4];                                                    \
    _Pragma("unroll") for (int mi2 = 0; mi2 < 4; ++mi2) {                   \
      af[mi2] = *(const short8*)&cA[((mh) * 128 + wr * 64 + mi2 * 16 +      \
                                     u16) * 64 + sl0];                      \
      af[4 + mi2] = *(const short8*)&cA[((mh) * 128 + wr * 64 + mi2 * 16 +  \
                                         u16) * 64 + sl1];                  \
    }                                                                       \
    _Pragma("unroll") for (int ni2 = 0; ni2 < 2; ++ni2) {                   \
      bf[ni2] = *(const short8*)&cB[(wc * 64 + (nh) * 32 + ni2 * 16 +       \
                                     u16) * 64 + sl0];                      \
      bf[2 + ni2] = *(const short8*)&cB[(wc * 64 + (nh) * 32 + ni2 * 16 +   \
                                         u16) * 64 + sl1];                  \
    }                                                                       \
    STAGE_STMT;                                                             \
    ASM_BARRIER();                                                          \
    __builtin_amdgcn_s_setprio(1);                                          \
    _Pragma("unroll") for (int mi2 = 0; mi2 < 4; ++mi2)                     \
        _Pragma("unroll") for (int ni2 = 0; ni2 < 2; ++ni2) {               \
      acc[(mh) * 4 + mi2][(nh) * 2 + ni2] =                                 \
          __builtin_amdgcn_mfma_f32_16x16x32_bf16(                          \
              af[mi2], bf[ni2], acc[(mh) * 4 + mi2][(nh) * 2 + ni2],        \
              0, 0, 0);                                                     \
      acc[(mh) * 4 + mi2][(nh) * 2 + ni2] =                                 \
          __builtin_amdgcn_mfma_f32_16x16x32_bf16(                          \
              af[4 + mi2], bf[2 + ni2],                                     \
              acc[(mh) * 4 + mi2][(nh) * 2 + ni2], 0, 0, 0);                \
    }                                                                       \
    __builtin_amdgcn_s_setprio(0);                                          \
    VM_STMT;                                                                \
    ASM_BARRIER();                                                          \
  }

// Common per-block geometry setup (identical in both kernels)
#define LSTM_SETUP()                                                        \
  const int tid = threadIdx.x;                                              \
  const int wid = tid >> 6;                                                 \
  const int lane = tid & 63;                                                \
  const int wr = wid >> 2;                                                  \
  const int wc = wid & 3;                                                   \
  const int u16 = lane & 15;                                                \
  const int k16q = lane >> 4;                                               \
  const int u7 = u16 & 7;                                                   \
  const int sl0 = (k16q ^ u7) * 8;                                          \
  const int sl1 = ((4 + k16q) ^ u7) * 8;                                    \
  const int bid = blockIdx.x;                                               \
  const int mt = (bid & 7) * 2 + ((bid >> 3) & 1);                          \
  const int jt = bid >> 4;                                                  \
  const int m0 = mt * 256;                                                  \
  const int lrow = lane >> 3;                                               \
  const int swcol = ((lane & 7) ^ lrow) * 8;                                \
  size_t aSrc[2];                                                           \
  size_t bSrc[2][2];                                                        \
  int aDst[2];                                                              \
  int bDst[2][2];                                                           \
  _Pragma("unroll") for (int q = 0; q < 2; ++q) {                           \
    const int g = wid * 2 + q;                                              \
    aSrc[q] = (size_t)(m0 + g * 8 + lrow) * HDIM + swcol;                   \
    aDst[q] = g * 1024;                                                     \
    _Pragma("unroll") for (int h = 0; h < 2; ++h) {                         \
      const int R = (g >> 2) * 64 + h * 32 + (g & 3) * 8;                   \
      const int n = R + lrow;                                               \
      const int gate = (n >> 4) & 3;                                        \
      const int uo = (n >> 6) * 16 + (n & 15);                              \
      bSrc[h][q] = (size_t)(gate * HDIM + jt * 64 + uo) * HDIM + swcol;     \
      bDst[h][q] = 32768 + R * 128;                                         \
    }                                                                       \
  }

// One full LSTM step body: prologue, 16 K-iters, cpre+Pb, epilogue.
// Reads: hprev, c_in_p, ids_t. Writes: c_out_p, hnext, (last) hf32_p.
#define LSTM_STEP_BODY(IS_LAST)                                             \
  {                                                                         \
    STAGE_A(0, 0, 0);                                                       \
    STAGE_B(0, 0, 0);                                                       \
    STAGE_A(1, 0, 0);                                                       \
    STAGE_B(1, 0, 0);                                                       \
    STAGE_A(0, 1, 1);                                                       \
    STAGE_B(0, 1, 1);                                                       \
    ASM_VMCNT4();                                                           \
    ASM_BARRIER();                                                          \
    f32x4 acc[8][4] = {};                                                   \
    _Pragma("unroll 2") for (int k = 0; k < 16; ++k) {                      \
      const int b = k & 1;                                                  \
      const int nb = b ^ 1;                                                 \
      const __hip_bfloat16* cA = (const __hip_bfloat16*)(smem + (b << 16)); \
      const __hip_bfloat16* cB =                                            \
          (const __hip_bfloat16*)(smem + (b << 16) + 32768);                \
      PHASE(0, 0, { if (k < 15) STAGE_A(1, k + 1, nb); }, {});              \
      PHASE(0, 1, { if (k < 15) STAGE_B(1, k + 1, nb); }, {});              \
      PHASE(1, 0, { if (k < 14) STAGE_A(0, k + 2, b); }, {});               \
      PHASE(1, 1, { if (k < 14) STAGE_B(0, k + 2, b); }, {                  \
        if (k < 14) { ASM_VMCNT4(); } else if (k == 14) { ASM_VMCNT0(); }   \
      });                                                                   \
    }                                                                       \
    const int jcol = jt * 64 + wc * 16 + u16;                               \
    float cpre[8][4];                                                       \
    _Pragma("unroll") for (int mi = 0; mi < 8; ++mi)                        \
        _Pragma("unroll") for (int r = 0; r < 4; ++r)                       \
            cpre[mi][r] = c_in_p[(size_t)(m0 + (mi >> 2) * 128 + wr * 64 +  \
                                          (mi & 3) * 16 + k16q * 4 + r) *   \
                                     HDIM +                                 \
                                 jcol];                                     \
    {                                                                       \
      const __hip_bfloat16* Pbj = Pb + (size_t)jt * 24576;                  \
      _Pragma("unroll") for (int i = 0; i < 6; ++i)                         \
          GLL16(Pbj + (wid * 6 + i) * 512 + lane * 8,                       \
                smem + (wid * 6 + i) * 1024);                               \
    }                                                                       \
    ASM_VMCNT0();                                                           \
    ASM_BARRIER();                                                          \
    const __hip_bfloat16* sPb = (const __hip_bfloat16*)smem;                \
    const int uo4 = (wc * 16 + u16) * 4;                                    \
    const int rb = m0 + wr * 64 + k16q * 4;                                 \
    _Pragma("unroll") for (int mi = 0; mi < 8; ++mi) {                      \
      _Pragma("unroll") for (int r = 0; r < 4; ++r) {                       \
        const int row = rb + (mi >> 2) * 128 + (mi & 3) * 16 + r;           \
        const int id = ids_t[row];                                          \
        const shortx4 pv = *(const shortx4*)&sPb[id * 256 + uo4];           \
        float iv = acc[mi][0][r] + b2f(pv[0]);                              \
        float fv = acc[mi][1][r] + b2f(pv[1]);                              \
        float gv = acc[mi][2][r] + b2f(pv[2]);                              \
        float ov = acc[mi][3][r] + b2f(pv[3]);                              \
        iv = sigmoidf_fast(iv);                                             \
        fv = sigmoidf_fast(fv);                                             \
        gv = tanhf_fast(gv);                                                \
        ov = sigmoidf_fast(ov);                                             \
        const size_t off = (size_t)row * HDIM + jcol;                       \
        const float cc = fv * cpre[mi][r] + iv * gv;                        \
        c_out_p[off] = cc;                                                  \
        const float hh = ov * tanhf_fast(cc);                               \
        hnext[off] = __float2bfloat16(hh);                                  \
        if (IS_LAST) hf32_p[off] = hh;                                      \
      }                                                                     \
    }                                                                       \
  }

// ---- persistent 21-step LSTM: 1 launch, per-mt-group barriers -----------
// Grid 256 = 1 block/CU (LDS 128KB forces 1/CU) -> all blocks co-resident.
// Cross-step dep: block (mt,jt) at t+1 reads h rows of mt only -> 16-block
// group barrier (atomic counter, monotonic to 16*20; prep zeroes each
// replay). Release: __syncthreads() drains each wave's stores to L2, then
// tid0 RMW with RELEASE (wbl2). Spin: fetch_add(0, RELAXED) -- RMW goes to
// the coherent point, immune to stale clean L2 lines. One ACQUIRE load
// (cache inv) before __syncthreads releases the block.
__global__ __launch_bounds__(512, 2) void lstm_persistent(
    const int* __restrict__ ids,               // T x B
    const __hip_bfloat16* __restrict__ Whh,    // 4H x H
    const __hip_bfloat16* __restrict__ Pb,     // 16 x 96 x 64 x 4
    const float* __restrict__ c0,              // B x H
    float* __restrict__ cT,                    // B x H (in-place after t=0)
    __hip_bfloat16* __restrict__ hts,          // (T+1) x B x H history
    float* __restrict__ hT,                    // B x H fp32 (last)
    int* __restrict__ bars)                    // 16 counters
{
  __shared__ __align__(16) char smem[131072];
  LSTM_SETUP();
  const size_t BH = (size_t)BSZ * HDIM;

#pragma unroll 1
  for (int t = 0; t < T_STEPS; ++t) {
    const __hip_bfloat16* hprev = hts + (size_t)t * BH;
    __hip_bfloat16* hnext = hts + (size_t)(t + 1) * BH;
    const float* c_in_p = (t == 0) ? c0 : cT;
    float* c_out_p = cT;
    const int* ids_t = ids + (size_t)t * BSZ;
    float* hf32_p = hT;
    const bool last = (t == T_STEPS - 1);

    LSTM_STEP_BODY(last);

    if (t < T_STEPS - 1) {
      __syncthreads();  // compiler-drained: all waves' stores in L2
      if (tid == 0) {
        __hip_atomic_fetch_add(&bars[mt], 1, __ATOMIC_RELEASE,
                               __HIP_MEMORY_SCOPE_AGENT);
        const int target = 16 * (t + 1);
        while (__hip_atomic_fetch_add(&bars[mt], 0, __ATOMIC_RELAXED,
                                      __HIP_MEMORY_SCOPE_AGENT) < target)
          __builtin_amdgcn_s_sleep(2);
        (void)__hip_atomic_load(&bars[mt], __ATOMIC_ACQUIRE,
                                __HIP_MEMORY_SCOPE_AGENT);
      }
      __syncthreads();
    }
  }
}

// ---- fallback single-step kernel (small-ws path), R4-verified -----------
template <bool LAST>
__global__ __launch_bounds__(512, 2) void lstm_step_kernel(
    const int* __restrict__ ids_t,
    const __hip_bfloat16* __restrict__ hprev,
    const __hip_bfloat16* __restrict__ Whh,
    const __hip_bfloat16* __restrict__ Pb,
    const float* __restrict__ c_in_p,
    float* __restrict__ c_out_p,
    __hip_bfloat16* __restrict__ hnext,
    float* __restrict__ hf32_p) {
  __shared__ __align__(16) char smem[131072];
  LSTM_SETUP();
  LSTM_STEP_BODY(LAST);
}

// ---- scores: LDS-tiled GEMM, 128 rows x 96 cols per block, BK=128 -------
__global__ __launch_bounds__(256, 2) void scores_kernel(
    const __hip_bfloat16* __restrict__ h,     // rows x H (bf16)
    const __hip_bfloat16* __restrict__ Wout,  // 96 x H
    const float* __restrict__ bout,           // 96
    float* __restrict__ out)                  // rows x 96
{
  __shared__ __align__(16) __hip_bfloat16 sA[128 * 128];  // 32 KB
  __shared__ __align__(16) __hip_bfloat16 sB[96 * 128];   // 24 KB

  const int tid = threadIdx.x;
  const int wave = tid >> 6, lane = tid & 63;
  const int u16 = lane & 15, k16q = lane >> 4;
  const long r0 = (long)blockIdx.x * 128;

  f32x4 acc[2][6] = {};  // wave: 32 rows x 96 cols

  const int srow4 = lane >> 4;
  const int sslot = lane & 15;

  for (int k0 = 0; k0 < HDIM; k0 += 128) {
#pragma unroll
    for (int i = 0; i < 8; ++i) {  // A: 32 rows/wave
      int row = wave * 32 + i * 4 + srow4;
      int gg = sslot ^ (row & 15);
      GLL16(h + (r0 + row) * HDIM + k0 + gg * 8,
            &sA[(wave * 32 + i * 4) * 128]);
    }
#pragma unroll
    for (int i = 0; i < 6; ++i) {  // B: 24 rows/wave
      int row = wave * 24 + i * 4 + srow4;
      int gg = sslot ^ (row & 15);
      GLL16(Wout + (size_t)row * HDIM + k0 + gg * 8,
            &sB[(wave * 24 + i * 4) * 128]);
    }
    __syncthreads();
#pragma unroll
    for (int kk = 0; kk < 128; kk += 32) {
      const int sl = (((kk >> 3) + k16q) ^ u16) * 8;
      short8 af[2], bf[6];
#pragma unroll
      for (int mi = 0; mi < 2; ++mi)
        af[mi] = *(const short8*)&sA[(wave * 32 + mi * 16 + u16) * 128 + sl];
#pragma unroll
      for (int ni = 0; ni < 6; ++ni)
        bf[ni] = *(const short8*)&sB[(ni * 16 + u16) * 128 + sl];
#pragma unroll
      for (int mi = 0; mi < 2; ++mi)
#pragma unroll
        for (int ni = 0; ni < 6; ++ni)
          acc[mi][ni] = __builtin_amdgcn_mfma_f32_16x16x32_bf16(
              af[mi], bf[ni], acc[mi][ni], 0, 0, 0);
    }
    __syncthreads();
  }

#pragma unroll
  for (int ni = 0; ni < 6; ++ni) {
    int v = ni * 16 + u16;
    float bv = bout[v];
#pragma unroll
    for (int mi = 0; mi < 2; ++mi)
#pragma unroll
      for (int r = 0; r < 4; ++r) {
        long grow = r0 + wave * 32 + mi * 16 + k16q * 4 + r;
        out[grow * VOCAB + v] = acc[mi][ni][r] + bv;
      }
  }
}

extern "C" void kernel_launch(void* const* d_in, const int* in_sizes, int n_in,
                              void* d_out, int out_size, void* d_ws,
                              size_t ws_size, hipStream_t stream) {
  const int* ids = (const int*)d_in[0];
  const float* h0 = (const float*)d_in[1];
  const float* c0 = (const float*)d_in[2];
  const float* emb = (const float*)d_in[3];
  const float* Wih = (const float*)d_in[4];
  const float* Whh_f = (const float*)d_in[5];
  const float* bih = (const float*)d_in[6];
  const float* bhh = (const float*)d_in[7];
  const float* Wout_f = (const float*)d_in[8];
  const float* bout = (const float*)d_in[9];

  float* out = (float*)d_out;
  float* scores = out;                              // T*B*V
  float* hT = out + (size_t)T_STEPS * BSZ * VOCAB;  // B*H
  float* cT = hT + (size_t)BSZ * HDIM;              // B*H

  const size_t BH = (size_t)BSZ * HDIM;
  char* w = (char*)d_ws;
  int* bars = (int*)w;                       w += 256;
  __hip_bfloat16* Pb = (__hip_bfloat16*)w;   w += (size_t)16 * 24576 * 2;
  __hip_bfloat16* Whh = (__hip_bfloat16*)w;  w += (size_t)4 * HDIM * HDIM * 2;
  __hip_bfloat16* Wout = (__hip_bfloat16*)w; w += (size_t)VOCAB * HDIM * 2;
  __hip_bfloat16* hts = (__hip_bfloat16*)w;  // 22*BH (full) or 2*BH (pingpong)
  size_t base = 256 + (size_t)16 * 24576 * 2 + (size_t)4 * HDIM * HDIM * 2 +
                (size_t)VOCAB * HDIM * 2;
  const bool full = ws_size >= base + (size_t)(T_STEPS + 1) * BH * 2;

  prep_convert<<<dim3((4 * HDIM * HDIM + 255) / 256), dim3(256), 0, stream>>>(
      Whh_f, Wout_f, h0, Whh, Wout, hts, bars);
  prep_ptable<<<dim3((VOCAB * 4096) / 256), dim3(256), 0, stream>>>(
      emb, Wih, bih, bhh, Pb);

  if (full) {
    lstm_persistent<<<dim3(256), dim3(512), 0, stream>>>(
        ids, Whh, Pb, c0, cT, hts, hT, bars);
    scores_kernel<<<dim3(T_STEPS * BSZ / 128), dim3(256), 0, stream>>>(
        hts + BH, Wout, bout, scores);
  } else {
    for (int t = 0; t < T_STEPS; ++t) {
      __hip_bfloat16* hp = hts + (size_t)(t & 1) * BH;
      __hip_bfloat16* hn = hts + (size_t)((t + 1) & 1) * BH;
      const float* cin = (t == 0) ? c0 : cT;
      if (t == T_STEPS - 1) {
        lstm_step_kernel<true><<<dim3(256), dim3(512), 0, stream>>>(
            ids + (size_t)t * BSZ, hp, Whh, Pb, cin, cT, hn, hT);
      } else {
        lstm_step_kernel<false><<<dim3(256), dim3(512), 0, stream>>>(
            ids + (size_t)t * BSZ, hp, Whh, Pb, cin, cT, hn, nullptr);
      }
      scores_kernel<<<dim3(BSZ / 128), dim3(256), 0, stream>>>(
          hn, Wout, bout, scores + (size_t)t * BSZ * VOCAB);
    }
  }
}

// Round 6
// 1106.312 us; speedup vs baseline: 1.7993x; 1.7993x over previous
//
#include <hip/hip_runtime.h>
#include <hip/hip_bf16.h>

// CharDecoder: T=21, B=4096, H=1024, E=50, V=96
// d_out: scores(T,B,V) fp32 | h_T(B,H) | c_T(B,H)

#define T_STEPS 21
#define BSZ 4096
#define HDIM 1024
#define VOCAB 96
#define EDIM 50

typedef __attribute__((ext_vector_type(8))) short short8;
typedef __attribute__((ext_vector_type(4))) short shortx4;
typedef __attribute__((ext_vector_type(4))) float f32x4;

#define GLL16(g, l)                                                        \
  __builtin_amdgcn_global_load_lds(                                        \
      (const __attribute__((address_space(1))) void*)(g),                  \
      (__attribute__((address_space(3))) void*)(l), 16, 0, 0)

#define ASM_BARRIER() asm volatile("s_barrier" ::: "memory")
#define ASM_VMCNT6() asm volatile("s_waitcnt vmcnt(6)" ::: "memory")
#define ASM_VMCNT0() asm volatile("s_waitcnt vmcnt(0)" ::: "memory")

__device__ __forceinline__ float sigmoidf_fast(float x) {
  return 1.0f / (1.0f + __expf(-x));
}
__device__ __forceinline__ float tanhf_fast(float x) {
  return 2.0f / (1.0f + __expf(-2.0f * x)) - 1.0f;
}
__device__ __forceinline__ float b2f(short s) {
  return __uint_as_float(((unsigned int)(unsigned short)s) << 16);
}

// ---- prep: fp32 -> bf16 weight/state conversion -------------------------
__global__ void prep_convert(const float* __restrict__ Whh_f,
                             const float* __restrict__ Wout_f,
                             const float* __restrict__ h0,
                             __hip_bfloat16* __restrict__ Whh,
                             __hip_bfloat16* __restrict__ Wout,
                             __hip_bfloat16* __restrict__ hb0) {
  int idx = blockIdx.x * 256 + threadIdx.x;
  if (idx < 4 * HDIM * HDIM) {
    Whh[idx] = __float2bfloat16(Whh_f[idx]);
    hb0[idx] = __float2bfloat16(h0[idx]);
  }
  if (idx < VOCAB * HDIM) Wout[idx] = __float2bfloat16(Wout_f[idx]);
}

// ---- prep: Pb[j>>6][v][unit 64][gate 4] (bf16) = emb.W_ih + b_ih + b_hh -
__global__ void prep_ptable(const float* __restrict__ emb,
                            const float* __restrict__ Wih,
                            const float* __restrict__ bih,
                            const float* __restrict__ bhh,
                            __hip_bfloat16* __restrict__ Pb) {
  int idx = blockIdx.x * 256 + threadIdx.x;  // 96*4096
  int v = idx >> 12, g = idx & 4095;         // g = gate*1024 + j
  int gate = g >> 10, j = g & 1023;
  const float* er = emb + v * EDIM;
  const float* wr = Wih + g * EDIM;
  float s = bih[g] + bhh[g];
#pragma unroll 10
  for (int e = 0; e < EDIM; ++e) s += er[e] * wr[e];
  Pb[(size_t)(j >> 6) * 24576 + v * 256 + (j & 63) * 4 + gate] =
      __float2bfloat16(s);
}

// ---- 256x256 LSTM step, 2 phases per K-tile ----------------------------
// Tile: 256 batch rows x (4 gates x 64 units); BK=64; 8 waves (2M x 4N);
// LDS 128 KiB = 2 buffers x (A 256x64 + B 256x64) bf16.
// Minimum-read schedule (24 ds_read_b128 / wave / K-tile):
//   ph1: read a0[8]+b0[4]+b1[4]; MFMA quadrants (0,0)+(0,1)  [32 MFMA]
//   ph2: read a1[8]; REUSE b0/b1 (32 VGPR across one barrier);
//        MFMA (1,0)+(1,1)                                    [32 MFMA]
// vs R4: LDS reads halved (48->24), barriers halved (8->4/K-tile),
// MFMA run per barrier doubled (16->32). R3's spill trap avoided: only
// b-frags (32 VGPR) are held across a barrier, a-frags stay transient.
// Staging (8 GLL16 / K-tile):
//   ph1 stages A-h1(k+1)->nb: region last read iter k-1 ph2    -> safe
//   ph2 stages A-h0(k+2)+B(k+2)->cur: A-h0/B last read this ph1 -> safe
// vmcnt proof (one counted wait per K-tile, at ph2 end):
//   issue order ... [k-1 ph2: 6 of tile k+1] [k ph1: 2 of tile k+1]
//   [k ph2: 6 of tile k+2]; vmcnt(6) leaves the newest 6 -> tile k+1
//   fully landed before iter k+1 ph1 reads it. k==14: vmcnt(0) (no stage).

#define STAGE_A(h, kt, b)                                                   \
  do {                                                                      \
    GLL16(hprev + aSrc[0] + (size_t)(h) * 131072 + (size_t)(kt) * 64,       \
          smem + ((b) << 16) + ((h) << 14) + aDst[0]);                      \
    GLL16(hprev + aSrc[1] + (size_t)(h) * 131072 + (size_t)(kt) * 64,       \
          smem + ((b) << 16) + ((h) << 14) + aDst[1]);                      \
  } while (0)

#define STAGE_B(h, kt, b)                                                   \
  do {                                                                      \
    GLL16(Whh + bSrc[h][0] + (size_t)(kt) * 64,                             \
          smem + ((b) << 16) + bDst[h][0]);                                 \
    GLL16(Whh + bSrc[h][1] + (size_t)(kt) * 64,                             \
          smem + ((b) << 16) + bDst[h][1]);                                 \
  } while (0)

#define LOAD_A(dst, mh)                                                     \
  _Pragma("unroll") for (int mi2 = 0; mi2 < 4; ++mi2) {                     \
    dst[mi2] = *(const short8*)&cA[((mh) * 128 + wr * 64 + mi2 * 16 +       \
                                    u16) * 64 + sl0];                       \
    dst[4 + mi2] = *(const short8*)&cA[((mh) * 128 + wr * 64 + mi2 * 16 +   \
                                        u16) * 64 + sl1];                   \
  }

#define LOAD_B(dst, nh)                                                     \
  _Pragma("unroll") for (int ni2 = 0; ni2 < 2; ++ni2) {                     \
    dst[ni2] = *(const short8*)&cB[(wc * 64 + (nh) * 32 + ni2 * 16 +        \
                                    u16) * 64 + sl0];                       \
    dst[2 + ni2] = *(const short8*)&cB[(wc * 64 + (nh) * 32 + ni2 * 16 +    \
                                        u16) * 64 + sl1];                   \
  }

#define MFMA_HALF(mh, nh, A, Bv)                                            \
  _Pragma("unroll") for (int mi2 = 0; mi2 < 4; ++mi2)                       \
      _Pragma("unroll") for (int ni2 = 0; ni2 < 2; ++ni2) {                 \
    acc[(mh) * 4 + mi2][(nh) * 2 + ni2] =                                   \
        __builtin_amdgcn_mfma_f32_16x16x32_bf16(                            \
            A[mi2], Bv[ni2], acc[(mh) * 4 + mi2][(nh) * 2 + ni2], 0, 0, 0); \
    acc[(mh) * 4 + mi2][(nh) * 2 + ni2] =                                   \
        __builtin_amdgcn_mfma_f32_16x16x32_bf16(                            \
            A[4 + mi2], Bv[2 + ni2], acc[(mh) * 4 + mi2][(nh) * 2 + ni2],   \
            0, 0, 0);                                                       \
  }

template <bool LAST>
__global__ __launch_bounds__(512, 2) void lstm_step_kernel(
    const int* __restrict__ ids,               // B ints (this t)
    const __hip_bfloat16* __restrict__ hprev,  // B x H
    const __hip_bfloat16* __restrict__ Whh,    // 4H x H (torch order i,f,g,o)
    const __hip_bfloat16* __restrict__ Pb,     // 16 x 96 x 64 x 4 (bf16)
    const float* __restrict__ c_in,            // B x H
    float* __restrict__ c_out,                 // B x H
    __hip_bfloat16* __restrict__ hnext,        // B x H
    float* __restrict__ hf32)                  // B x H (LAST only)
{
  __shared__ __align__(16) char smem[131072];

  const int tid = threadIdx.x;
  const int wid = tid >> 6;
  const int lane = tid & 63;
  const int wr = wid >> 2;  // 0..1  (M half of wave grid)
  const int wc = wid & 3;   // 0..3  (N quarter)
  const int u16 = lane & 15;
  const int k16q = lane >> 4;
  const int u7 = u16 & 7;
  const int sl0 = (k16q ^ u7) * 8;        // kk=0..31 slot
  const int sl1 = ((4 + k16q) ^ u7) * 8;  // kk=32..63 slot

  // XCD swizzle: the 16 jt-blocks sharing an A panel (same mt) land on one
  // XCD -> A panel + produced h stay in that XCD's L2.
  const int bid = blockIdx.x;
  const int mt = (bid & 7) * 2 + ((bid >> 3) & 1);  // 0..15
  const int jt = bid >> 4;                          // 0..15 (64-unit block)
  const int m0 = mt * 256;

  // staging lane decomposition: 8 rows x 8 swizzled 16B slots per GLL16
  const int lrow = lane >> 3;
  const int swcol = ((lane & 7) ^ lrow) * 8;

  // per-thread staging bases. A group g = wid*2+q covers LDS rows
  // h*128 + g*8 .. +8. B group g covers LDS rows R..R+8 with
  // R = (g>>2)*64 + h*32 + (g&3)*8.
  size_t aSrc[2];
  size_t bSrc[2][2];
  int aDst[2];
  int bDst[2][2];
#pragma unroll
  for (int q = 0; q < 2; ++q) {
    const int g = wid * 2 + q;
    aSrc[q] = (size_t)(m0 + g * 8 + lrow) * HDIM + swcol;
    aDst[q] = g * 1024;
#pragma unroll
    for (int h = 0; h < 2; ++h) {
      const int R = (g >> 2) * 64 + h * 32 + (g & 3) * 8;
      const int n = R + lrow;  // LDS B row
      const int gate = (n >> 4) & 3;
      const int uo = (n >> 6) * 16 + (n & 15);
      bSrc[h][q] = (size_t)(gate * HDIM + jt * 64 + uo) * HDIM + swcol;
      bDst[h][q] = 32768 + R * 128;
    }
  }

  // prologue: K-tile 0 fully (8), then A-h0 + B of K-tile 1 (6)
  STAGE_A(0, 0, 0);
  STAGE_A(1, 0, 0);
  STAGE_B(0, 0, 0);
  STAGE_B(1, 0, 0);
  STAGE_A(0, 1, 1);
  STAGE_B(0, 1, 1);
  STAGE_B(1, 1, 1);

  ASM_VMCNT6();  // K-tile 0 landed; tile1's 6 may stay in flight
  ASM_BARRIER();

  f32x4 acc[8][4] = {};  // [M-frag][gate]

#pragma unroll 2
  for (int k = 0; k < 16; ++k) {
    const int b = k & 1;
    const int nb = b ^ 1;
    const __hip_bfloat16* cA = (const __hip_bfloat16*)(smem + (b << 16));
    const __hip_bfloat16* cB =
        (const __hip_bfloat16*)(smem + (b << 16) + 32768);

    // ---- ph1: a0 + b0 + b1 (16 reads), quadrants (0,*) ----
    short8 a0[8], b0[4], b1[4];
    LOAD_A(a0, 0);
    LOAD_B(b0, 0);
    LOAD_B(b1, 1);
    if (k < 15) STAGE_A(1, k + 1, nb);
    ASM_BARRIER();
    __builtin_amdgcn_s_setprio(1);
    MFMA_HALF(0, 0, a0, b0);
    MFMA_HALF(0, 1, a0, b1);
    __builtin_amdgcn_s_setprio(0);
    ASM_BARRIER();

    // ---- ph2: a1 (8 reads), reuse b0/b1, quadrants (1,*) ----
    short8 a1[8];
    LOAD_A(a1, 1);
    if (k < 14) {
      STAGE_A(0, k + 2, b);
      STAGE_B(0, k + 2, b);
      STAGE_B(1, k + 2, b);
    }
    ASM_BARRIER();
    __builtin_amdgcn_s_setprio(1);
    MFMA_HALF(1, 0, a1, b0);
    MFMA_HALF(1, 1, a1, b1);
    __builtin_amdgcn_s_setprio(0);
    if (k < 14) {
      ASM_VMCNT6();  // tile k+1 fully landed; tile k+2's 6 in flight
    } else if (k == 14) {
      ASM_VMCNT0();  // drain tail (no stages at k=14 ph2)
    }
    ASM_BARRIER();
  }

  // c_in prefetch (overlaps Pb staging + barrier below). Each block owns a
  // disjoint (row, jcol) tile of c, so load-then-store is race-free.
  const int jcol = jt * 64 + wc * 16 + u16;  // output unit j
  float cpre[8][4];
#pragma unroll
  for (int mi = 0; mi < 8; ++mi)
#pragma unroll
    for (int r = 0; r < 4; ++r)
      cpre[mi][r] = c_in[(size_t)(m0 + (mi >> 2) * 128 + wr * 64 +
                                  (mi & 3) * 16 + k16q * 4 + r) *
                             HDIM +
                         jcol];

  // stage bf16 P slice (48 KB) into now-dead LDS; no GLL16s outstanding.
  {
    const __hip_bfloat16* Pbj = Pb + (size_t)jt * 24576;
#pragma unroll
    for (int i = 0; i < 6; ++i)
      GLL16(Pbj + (wid * 6 + i) * 512 + lane * 8,
            smem + (wid * 6 + i) * 1024);
  }
  ASM_VMCNT0();
  ASM_BARRIER();

  // epilogue: all 4 gates of unit jcol contiguous -> one b64 gather
  const __hip_bfloat16* sPb = (const __hip_bfloat16*)smem;
  const int uo4 = (wc * 16 + u16) * 4;
  const int rb = m0 + wr * 64 + k16q * 4;
#pragma unroll
  for (int mi = 0; mi < 8; ++mi) {
#pragma unroll
    for (int r = 0; r < 4; ++r) {
      const int row = rb + (mi >> 2) * 128 + (mi & 3) * 16 + r;
      const int id = ids[row];
      const shortx4 pv = *(const shortx4*)&sPb[id * 256 + uo4];
      float iv = acc[mi][0][r] + b2f(pv[0]);
      float fv = acc[mi][1][r] + b2f(pv[1]);
      float gv = acc[mi][2][r] + b2f(pv[2]);
      float ov = acc[mi][3][r] + b2f(pv[3]);
      iv = sigmoidf_fast(iv);
      fv = sigmoidf_fast(fv);
      gv = tanhf_fast(gv);
      ov = sigmoidf_fast(ov);
      const size_t off = (size_t)row * HDIM + jcol;
      const float cc = fv * cpre[mi][r] + iv * gv;
      c_out[off] = cc;
      const float hh = ov * tanhf_fast(cc);
      hnext[off] = __float2bfloat16(hh);
      if (LAST) hf32[off] = hh;
    }
  }
}

// ---- scores: LDS-tiled GEMM, 128 rows x 96 cols per block, BK=128 -------
__global__ __launch_bounds__(256, 2) void scores_kernel(
    const __hip_bfloat16* __restrict__ h,     // rows x H (bf16)
    const __hip_bfloat16* __restrict__ Wout,  // 96 x H
    const float* __restrict__ bout,           // 96
    float* __restrict__ out)                  // rows x 96
{
  __shared__ __align__(16) __hip_bfloat16 sA[128 * 128];  // 32 KB
  __shared__ __align__(16) __hip_bfloat16 sB[96 * 128];   // 24 KB

  const int tid = threadIdx.x;
  const int wave = tid >> 6, lane = tid & 63;
  const int u16 = lane & 15, k16q = lane >> 4;
  const long r0 = (long)blockIdx.x * 128;

  f32x4 acc[2][6] = {};  // wave: 32 rows x 96 cols

  const int srow4 = lane >> 4;
  const int sslot = lane & 15;

  for (int k0 = 0; k0 < HDIM; k0 += 128) {
#pragma unroll
    for (int i = 0; i < 8; ++i) {  // A: 32 rows/wave
      int row = wave * 32 + i * 4 + srow4;
      int gg = sslot ^ (row & 15);
      GLL16(h + (r0 + row) * HDIM + k0 + gg * 8,
            &sA[(wave * 32 + i * 4) * 128]);
    }
#pragma unroll
    for (int i = 0; i < 6; ++i) {  // B: 24 rows/wave
      int row = wave * 24 + i * 4 + srow4;
      int gg = sslot ^ (row & 15);
      GLL16(Wout + (size_t)row * HDIM + k0 + gg * 8,
            &sB[(wave * 24 + i * 4) * 128]);
    }
    __syncthreads();
#pragma unroll
    for (int kk = 0; kk < 128; kk += 32) {
      const int sl = (((kk >> 3) + k16q) ^ u16) * 8;
      short8 af[2], bf[6];
#pragma unroll
      for (int mi = 0; mi < 2; ++mi)
        af[mi] = *(const short8*)&sA[(wave * 32 + mi * 16 + u16) * 128 + sl];
#pragma unroll
      for (int ni = 0; ni < 6; ++ni)
        bf[ni] = *(const short8*)&sB[(ni * 16 + u16) * 128 + sl];
#pragma unroll
      for (int mi = 0; mi < 2; ++mi)
#pragma unroll
        for (int ni = 0; ni < 6; ++ni)
          acc[mi][ni] = __builtin_amdgcn_mfma_f32_16x16x32_bf16(
              af[mi], bf[ni], acc[mi][ni], 0, 0, 0);
    }
    __syncthreads();
  }

#pragma unroll
  for (int ni = 0; ni < 6; ++ni) {
    int v = ni * 16 + u16;
    float bv = bout[v];
#pragma unroll
    for (int mi = 0; mi < 2; ++mi)
#pragma unroll
      for (int r = 0; r < 4; ++r) {
        long grow = r0 + wave * 32 + mi * 16 + k16q * 4 + r;
        out[grow * VOCAB + v] = acc[mi][ni][r] + bv;
      }
  }
}

extern "C" void kernel_launch(void* const* d_in, const int* in_sizes, int n_in,
                              void* d_out, int out_size, void* d_ws,
                              size_t ws_size, hipStream_t stream) {
  const int* ids = (const int*)d_in[0];
  const float* h0 = (const float*)d_in[1];
  const float* c0 = (const float*)d_in[2];
  const float* emb = (const float*)d_in[3];
  const float* Wih = (const float*)d_in[4];
  const float* Whh_f = (const float*)d_in[5];
  const float* bih = (const float*)d_in[6];
  const float* bhh = (const float*)d_in[7];
  const float* Wout_f = (const float*)d_in[8];
  const float* bout = (const float*)d_in[9];

  float* out = (float*)d_out;
  float* scores = out;                              // T*B*V
  float* hT = out + (size_t)T_STEPS * BSZ * VOCAB;  // B*H
  float* cT = hT + (size_t)BSZ * HDIM;              // B*H

  const size_t BH = (size_t)BSZ * HDIM;
  char* w = (char*)d_ws;
  __hip_bfloat16* Pb = (__hip_bfloat16*)w;   w += (size_t)16 * 24576 * 2;
  __hip_bfloat16* Whh = (__hip_bfloat16*)w;  w += (size_t)4 * HDIM * HDIM * 2;
  __hip_bfloat16* Wout = (__hip_bfloat16*)w; w += (size_t)VOCAB * HDIM * 2;
  __hip_bfloat16* hts = (__hip_bfloat16*)w;  // 22*BH (full) or 2*BH (pingpong)
  size_t base = (size_t)16 * 24576 * 2 + (size_t)4 * HDIM * HDIM * 2 +
                (size_t)VOCAB * HDIM * 2;
  const bool full = ws_size >= base + (size_t)(T_STEPS + 1) * BH * 2;

  prep_convert<<<dim3((4 * HDIM * HDIM + 255) / 256), dim3(256), 0, stream>>>(
      Whh_f, Wout_f, h0, Whh, Wout, hts);
  prep_ptable<<<dim3((VOCAB * 4096) / 256), dim3(256), 0, stream>>>(
      emb, Wih, bih, bhh, Pb);

  for (int t = 0; t < T_STEPS; ++t) {
    __hip_bfloat16* hp = hts + (full ? (size_t)t * BH : (size_t)(t & 1) * BH);
    __hip_bfloat16* hn =
        hts + (full ? (size_t)(t + 1) * BH : (size_t)((t + 1) & 1) * BH);
    const float* cin = (t == 0) ? c0 : cT;
    if (t == T_STEPS - 1) {
      lstm_step_kernel<true><<<dim3(256), dim3(512), 0, stream>>>(
          ids + (size_t)t * BSZ, hp, Whh, Pb, cin, cT, hn, hT);
    } else {
      lstm_step_kernel<false><<<dim3(256), dim3(512), 0, stream>>>(
          ids + (size_t)t * BSZ, hp, Whh, Pb, cin, cT, hn, nullptr);
    }
    if (!full) {
      scores_kernel<<<dim3(BSZ / 128), dim3(256), 0, stream>>>(
          hn, Wout, bout, scores + (size_t)t * BSZ * VOCAB);
    }
  }
  if (full) {
    scores_kernel<<<dim3(T_STEPS * BSZ / 128), dim3(256), 0, stream>>>(
        hts + BH, Wout, bout, scores);
  }
}